// Round 1
// baseline (214.588 us; speedup 1.0000x reference)
//
#include <hip/hip_runtime.h>

// Trilinear 3D warp: out[b,x,y,z] = trilerp(image[b], (x,y,z) + ddf[b,x,y,z,:])
// Dims fixed: B=4, F=M=(128,128,128).

#define DIM 128
#define DIM3 (128*128*128)

__global__ __launch_bounds__(256) void warp_kernel(
    const float* __restrict__ ddf,
    const float* __restrict__ image,
    float* __restrict__ out,
    int total)
{
    int idx = blockIdx.x * blockDim.x + threadIdx.x;
    if (idx >= total) return;

    // idx = b*128^3 + x*128^2 + y*128 + z
    int z = idx & (DIM - 1);
    int y = (idx >> 7) & (DIM - 1);
    int x = (idx >> 14) & (DIM - 1);
    int b = idx >> 21;

    const float* d = ddf + (size_t)idx * 3;
    float lx = (float)x + d[0];
    float ly = (float)y + d[1];
    float lz = (float)z + d[2];

    const float maxf = (float)(DIM - 1);
    lx = fminf(fmaxf(lx, 0.0f), maxf);
    ly = fminf(fmaxf(ly, 0.0f), maxf);
    lz = fminf(fmaxf(lz, 0.0f), maxf);

    float fx = floorf(lx), fy = floorf(ly), fz = floorf(lz);
    int ix0 = (int)fx, iy0 = (int)fy, iz0 = (int)fz;
    int ix1 = min(ix0 + 1, DIM - 1);
    int iy1 = min(iy0 + 1, DIM - 1);
    int iz1 = min(iz0 + 1, DIM - 1);

    float wx1 = lx - fx, wy1 = ly - fy, wz1 = lz - fz;
    float wx0 = 1.0f - wx1, wy0 = 1.0f - wy1, wz0 = 1.0f - wz1;

    const float* img = image + ((size_t)b << 21);
    int bx0 = ix0 << 14, bx1 = ix1 << 14;
    int by0 = iy0 << 7,  by1 = iy1 << 7;

    float c000 = img[bx0 + by0 + iz0];
    float c001 = img[bx0 + by0 + iz1];
    float c010 = img[bx0 + by1 + iz0];
    float c011 = img[bx0 + by1 + iz1];
    float c100 = img[bx1 + by0 + iz0];
    float c101 = img[bx1 + by0 + iz1];
    float c110 = img[bx1 + by1 + iz0];
    float c111 = img[bx1 + by1 + iz1];

    float r = wx0 * (wy0 * (wz0 * c000 + wz1 * c001) +
                     wy1 * (wz0 * c010 + wz1 * c011)) +
              wx1 * (wy0 * (wz0 * c100 + wz1 * c101) +
                     wy1 * (wz0 * c110 + wz1 * c111));

    out[idx] = r;
}

extern "C" void kernel_launch(void* const* d_in, const int* in_sizes, int n_in,
                              void* d_out, int out_size, void* d_ws, size_t ws_size,
                              hipStream_t stream) {
    const float* ddf   = (const float*)d_in[0];
    const float* image = (const float*)d_in[1];
    float* out = (float*)d_out;

    int total = out_size; // 4 * 128^3 = 8388608
    int block = 256;
    int grid = (total + block - 1) / block;
    warp_kernel<<<grid, block, 0, stream>>>(ddf, image, out, total);
}